// Round 1
// baseline (948.304 us; speedup 1.0000x reference)
//
#include <hip/hip_runtime.h>
#include <stdint.h>
#include <stddef.h>

#define TDIM 4096
#define DDIM 1024
#define HDIM 64
#define BDIM 8
#define MROWS (BDIM * TDIM)   // 32768
#define KCAT (DDIM + HDIM)    // 1088

typedef unsigned short ushort_t;
typedef __attribute__((ext_vector_type(8))) short short8;
typedef __attribute__((ext_vector_type(4))) float floatx4;

__device__ __forceinline__ unsigned short f2bf(float f) {
  unsigned u = __float_as_uint(f);
  u += 0x7fffu + ((u >> 16) & 1u);          // round-to-nearest-even
  return (unsigned short)(u >> 16);
}
__device__ __forceinline__ float bf2f(unsigned short s) {
  return __uint_as_float(((unsigned)s) << 16);
}
__device__ __forceinline__ float softplusf(float x) {
  return x > 20.f ? x : log1pf(expf(x));
}

// ---------------- weight conversion helpers ----------------
__global__ void k_cvt(const float* __restrict__ src, ushort_t* __restrict__ dst, int n) {
  int i = blockIdx.x * blockDim.x + threadIdx.x;
  if (i < n) dst[i] = f2bf(src[i]);
}

// Bcat[n][k] : k<1024 -> Dw[n][k], else Cw[n][k-1024]
__global__ void k_bcat(const float* __restrict__ Dw, const float* __restrict__ Cw,
                       ushort_t* __restrict__ bcat) {
  int i = blockIdx.x * blockDim.x + threadIdx.x;
  if (i >= DDIM * KCAT) return;
  int row = i / KCAT, k = i - row * KCAT;
  float v = (k < DDIM) ? Dw[row * DDIM + k] : Cw[row * HDIM + (k - DDIM)];
  bcat[i] = f2bf(v);
}

__global__ void k_bias(const float* __restrict__ Cb, const float* __restrict__ Db,
                       float* __restrict__ biasCD) {
  int i = blockIdx.x * blockDim.x + threadIdx.x;
  if (i < DDIM) biasCD[i] = Cb[i] + Db[i];
}

// ---------------- RMSNorm: x (f32) -> xn (bf16) ----------------
__global__ __launch_bounds__(256) void k_rms(const float* __restrict__ x,
                                             const float* __restrict__ nw,
                                             ushort_t* __restrict__ xn) {
  const int row = blockIdx.x;
  const int tid = threadIdx.x;
  const size_t base = (size_t)row * DDIM + tid * 4;
  const float4 xv = *(const float4*)(x + base);
  float ss = xv.x * xv.x + xv.y * xv.y + xv.z * xv.z + xv.w * xv.w;
  for (int off = 32; off > 0; off >>= 1) ss += __shfl_down(ss, off, 64);
  __shared__ float sws[4];
  const int lane = tid & 63, w = tid >> 6;
  if (lane == 0) sws[w] = ss;
  __syncthreads();
  const float tot = sws[0] + sws[1] + sws[2] + sws[3];
  const float scale = rsqrtf(tot * (1.0f / DDIM) + 1.1920929e-7f);
  const float4 nwv = *(const float4*)(nw + tid * 4);
  ushort4 o;
  o.x = f2bf(xv.x * scale * nwv.x);
  o.y = f2bf(xv.y * scale * nwv.y);
  o.z = f2bf(xv.z * scale * nwv.z);
  o.w = f2bf(xv.w * scale * nwv.w);
  *(ushort4*)(xn + base) = o;
}

// ---------------- causal depthwise conv k=3 + silu -> acat[:, 0:1024] ----------------
__global__ __launch_bounds__(256) void k_conv(const ushort_t* __restrict__ xb,
                                              const float* __restrict__ cw,
                                              const float* __restrict__ cb,
                                              ushort_t* __restrict__ acat) {
  const size_t idx = (size_t)blockIdx.x * 256 + threadIdx.x;  // over MROWS*DDIM
  const int d = (int)(idx & (DDIM - 1));
  const size_t m = idx >> 10;
  const int t = (int)(m & (TDIM - 1));
  const float w0 = cw[d * 3 + 0], w1 = cw[d * 3 + 1], w2 = cw[d * 3 + 2];
  float v = bf2f(xb[idx]) * w2;
  if (t >= 1) v += bf2f(xb[idx - DDIM]) * w1;
  if (t >= 2) v += bf2f(xb[idx - 2 * DDIM]) * w0;
  v += cb[d];
  const float s = v / (1.f + __expf(-v));
  acat[m * KCAT + d] = f2bf(s);
}

// ---------------- delta / A_bar_log / B_bar elementwise ----------------
__global__ __launch_bounds__(256) void k_delta(const float* __restrict__ preG,
                                               const float* __restrict__ db,
                                               const float* __restrict__ Bb,
                                               const float* __restrict__ A,
                                               float* __restrict__ Alog,
                                               float* __restrict__ Bbar) {
  const size_t idx = (size_t)blockIdx.x * 256 + threadIdx.x;  // over MROWS*HDIM
  const size_t m = idx >> 6;
  const int h = (int)(idx & (HDIM - 1));
  const float delta = softplusf(preG[m * 128 + h] + db[h]);
  const float al = -softplusf(A[h]);
  const float pb = preG[m * 128 + 64 + h] + Bb[h];
  Alog[idx] = delta * al;
  Bbar[idx] = delta * pb;
}

// ---------------- selective scan: one block per (b,h) channel ----------------
__global__ __launch_bounds__(256) void k_scan(const float* __restrict__ Alog,
                                              const float* __restrict__ Bbar,
                                              ushort_t* __restrict__ acat) {
  const int ch = blockIdx.x;           // 0..511
  const int b = ch >> 6, h = ch & 63;
  const int tid = threadIdx.x;
  const size_t idx0 = ((size_t)b * TDIM + (size_t)tid * 16) * HDIM + h;

  float a[16];
#pragma unroll
  for (int k = 0; k < 16; ++k) a[k] = Alog[idx0 + (size_t)k * HDIM];
  float run = 0.f;
#pragma unroll
  for (int k = 0; k < 16; ++k) { run += a[k]; a[k] = run; }  // local inclusive

  __shared__ float sh[256];
  sh[tid] = run;
  __syncthreads();
  for (int s = 1; s < 256; s <<= 1) {
    float v = (tid >= s) ? sh[tid - s] : 0.f;
    __syncthreads();
    sh[tid] += v;
    __syncthreads();
  }
  const float off = (tid > 0) ? sh[tid - 1] : 0.f;
  __syncthreads();

  float term[16];
  float prev = off;  // exclusive prefix (unclipped)
#pragma unroll
  for (int k = 0; k < 16; ++k) {
    const float Pk = off + a[k];
    const float Ashift = fminf(fmaxf(prev, -20.f), 20.f);
    const float bb = Bbar[idx0 + (size_t)k * HDIM];
    term[k] = bb * expf(-Ashift);
    a[k] = fminf(fmaxf(Pk, -20.f), 20.f);  // clipped A_cum
    prev = Pk;
  }

  float run2 = 0.f;
#pragma unroll
  for (int k = 0; k < 16; ++k) { run2 += term[k]; term[k] = run2; }
  sh[tid] = run2;
  __syncthreads();
  for (int s = 1; s < 256; s <<= 1) {
    float v = (tid >= s) ? sh[tid - s] : 0.f;
    __syncthreads();
    sh[tid] += v;
    __syncthreads();
  }
  const float off2 = (tid > 0) ? sh[tid - 1] : 0.f;

  const size_t mbase = (size_t)b * TDIM + (size_t)tid * 16;
#pragma unroll
  for (int k = 0; k < 16; ++k) {
    const float hval = expf(a[k]) * (off2 + term[k]);
    acat[(mbase + k) * KCAT + DDIM + h] = f2bf(hval);
  }
}

// ---------------- GEMM: C[m,n] = sum_k A[m,k] * Bt[n,k], bf16 MFMA ----------------
// 128x128 tile, BK=64, 256 threads (4 waves, each 64x64 as 4x4 16x16 frags).
// Staging via global_load_lds(16B) with XOR-chunk swizzle (dest chunk = src chunk ^ (row&7)).
__device__ __forceinline__ void stage128x64(const ushort_t* __restrict__ G, int row0,
                                            int ld, int kc, ushort_t* s, int wave, int lane) {
  const int rsub = lane >> 3;   // row within 8-row group
  const int cpos = lane & 7;    // dest chunk position
  using gp_t = const unsigned int __attribute__((address_space(1)))*;
  using lp_t = unsigned int __attribute__((address_space(3)))*;
#pragma unroll
  for (int g = 0; g < 4; ++g) {
    const int rg = wave * 4 + g;           // 0..15 row-group
    const int r = rg * 8 + rsub;           // tile row
    const int c = cpos ^ rsub;             // source chunk (r&7 == rsub)
    const ushort_t* src = G + (size_t)(row0 + r) * (size_t)ld + (size_t)(kc + c * 8);
    __builtin_amdgcn_global_load_lds((gp_t)(const void*)src, (lp_t)(void*)(s + rg * 512),
                                     16, 0, 0);
  }
}

__global__ __launch_bounds__(256, 2) void k_gemm(
    const ushort_t* __restrict__ A, int lda,
    const ushort_t* __restrict__ Bt, int ldb,
    int Ndim, int Kdim, int mode,
    float* __restrict__ outF, ushort_t* __restrict__ outB, int ldc,
    const float* __restrict__ bias,
    const ushort_t* __restrict__ zmat,
    const float* __restrict__ resid) {
  __shared__ alignas(16) ushort_t sA[128 * 64];
  __shared__ alignas(16) ushort_t sB[128 * 64];
  const int tid = threadIdx.x;
  const int wave = tid >> 6, lane = tid & 63;
  const int m0 = blockIdx.y * 128, n0 = blockIdx.x * 128;
  const int half_m = (wave & 1) * 64, half_n = (wave >> 1) * 64;
  const int quad = lane >> 4, l16 = lane & 15;

  floatx4 acc[4][4];
#pragma unroll
  for (int i = 0; i < 4; ++i)
#pragma unroll
    for (int j = 0; j < 4; ++j) acc[i][j] = floatx4{0.f, 0.f, 0.f, 0.f};

  for (int kc = 0; kc < Kdim; kc += 64) {
    stage128x64(A, m0, lda, kc, sA, wave, lane);
    stage128x64(Bt, n0, ldb, kc, sB, wave, lane);
    __syncthreads();
#pragma unroll
    for (int s = 0; s < 2; ++s) {
      short8 af[4], bfr[4];
#pragma unroll
      for (int i = 0; i < 4; ++i) {
        const int r = half_m + i * 16 + l16;
        const int cp = (s * 4 + quad) ^ (r & 7);
        af[i] = *(const short8*)(sA + r * 64 + cp * 8);
      }
#pragma unroll
      for (int j = 0; j < 4; ++j) {
        const int r = half_n + j * 16 + l16;
        const int cp = (s * 4 + quad) ^ (r & 7);
        bfr[j] = *(const short8*)(sB + r * 64 + cp * 8);
      }
#pragma unroll
      for (int i = 0; i < 4; ++i)
#pragma unroll
        for (int j = 0; j < 4; ++j)
          acc[i][j] = __builtin_amdgcn_mfma_f32_16x16x32_bf16(af[i], bfr[j], acc[i][j], 0, 0, 0);
    }
    __syncthreads();
  }

  // Epilogue. C/D layout: col = lane&15, row = quad*4 + reg (m89-verified).
#pragma unroll
  for (int i = 0; i < 4; ++i) {
#pragma unroll
    for (int j = 0; j < 4; ++j) {
#pragma unroll
      for (int rg = 0; rg < 4; ++rg) {
        const size_t m = (size_t)(m0 + half_m + i * 16 + quad * 4 + rg);
        const int n = n0 + half_n + j * 16 + l16;
        const float v = acc[i][j][rg];
        if (mode == 0) {
          outB[m * (size_t)ldc + n] = f2bf(v);
        } else if (mode == 1) {
          outF[m * (size_t)ldc + n] = v;
        } else if (mode == 2) {
          const float zf = bf2f(zmat[m * (size_t)Ndim + n]);
          const float u = (v + bias[n]) * (zf / (1.f + __expf(-zf)));
          outB[m * (size_t)ldc + n] = f2bf(u);
        } else {
          const size_t off = m * (size_t)Ndim + n;
          outF[off] = v + resid[off];
        }
      }
    }
  }
}

// ---------------- host ----------------
extern "C" void kernel_launch(void* const* d_in, const int* in_sizes, int n_in,
                              void* d_out, int out_size, void* d_ws, size_t ws_size,
                              hipStream_t stream) {
  const float* x      = (const float*)d_in[0];
  const float* norm_w = (const float*)d_in[1];
  const float* W1     = (const float*)d_in[2];
  const float* W2     = (const float*)d_in[3];
  const float* Wlast  = (const float*)d_in[4];
  const float* conv_w = (const float*)d_in[5];
  const float* conv_b = (const float*)d_in[6];
  const float* Aarr   = (const float*)d_in[7];
  const float* Bw     = (const float*)d_in[8];
  const float* Bb     = (const float*)d_in[9];
  const float* Cw     = (const float*)d_in[10];
  const float* Cb     = (const float*)d_in[11];
  const float* Dw     = (const float*)d_in[12];
  const float* Db     = (const float*)d_in[13];
  const float* dwm    = (const float*)d_in[14];
  const float* dbv    = (const float*)d_in[15];

  char* ws = (char*)d_ws;
  // buffer plan (bytes):
  ushort_t* xn   = (ushort_t*)(ws + 0);           // M*D bf16 (67MB); reused as u later
  ushort_t* xb   = (ushort_t*)(ws + 67108864);    // M*D bf16; reused as preG f32 later
  ushort_t* z    = (ushort_t*)(ws + 134217728);   // M*D bf16
  ushort_t* acat = (ushort_t*)(ws + 201326592);   // M*1088 bf16 (xc | h)
  float*   Alog  = (float*)(ws + 272629760);      // M*64 f32
  float*   Bbar  = (float*)(ws + 281018368);      // M*64 f32
  ushort_t* w1b  = (ushort_t*)(ws + 289406976);   // 1024*1024 bf16
  ushort_t* w2b  = (ushort_t*)(ws + 291504128);
  ushort_t* wlb  = (ushort_t*)(ws + 293601280);
  ushort_t* dwbw = (ushort_t*)(ws + 295698432);   // 128*1024 bf16 (dw rows 0..63, Bw 64..127)
  ushort_t* bcat = (ushort_t*)(ws + 295960576);   // 1024*1088 bf16 (Dw | Cw)
  float*   biasCD= (float*)(ws + 298188800);      // 1024 f32
  float*   preG  = (float*)xb;                    // M*128 f32 alias (xb dead by then)
  float*   outF  = (float*)d_out;

  // weight conversions
  k_cvt<<<4096, 256, 0, stream>>>(W1, w1b, DDIM * DDIM);
  k_cvt<<<4096, 256, 0, stream>>>(W2, w2b, DDIM * DDIM);
  k_cvt<<<4096, 256, 0, stream>>>(Wlast, wlb, DDIM * DDIM);
  k_cvt<<<256, 256, 0, stream>>>(dwm, dwbw, HDIM * DDIM);
  k_cvt<<<256, 256, 0, stream>>>(Bw, dwbw + HDIM * DDIM, HDIM * DDIM);
  k_bcat<<<(DDIM * KCAT + 255) / 256, 256, 0, stream>>>(Dw, Cw, bcat);
  k_bias<<<4, 256, 0, stream>>>(Cb, Db, biasCD);

  // 1. RMSNorm
  k_rms<<<MROWS, 256, 0, stream>>>(x, norm_w, xn);

  // 2. x_b = xn @ W1.T ; z = xn @ W2.T
  {
    dim3 g(DDIM / 128, MROWS / 128);
    k_gemm<<<g, 256, 0, stream>>>(xn, DDIM, w1b, DDIM, DDIM, DDIM, 0,
                                  nullptr, xb, DDIM, nullptr, nullptr, nullptr);
    k_gemm<<<g, 256, 0, stream>>>(xn, DDIM, w2b, DDIM, DDIM, DDIM, 0,
                                  nullptr, z, DDIM, nullptr, nullptr, nullptr);
  }

  // 3. conv + silu -> acat cols [0,1024)
  k_conv<<<(MROWS * DDIM) / 256, 256, 0, stream>>>(xb, conv_w, conv_b, acat);

  // 4. [delta_pre | Bbar_pre] = xc @ [dw|Bw].T  (N=128, f32 out)
  {
    dim3 g(1, MROWS / 128);
    k_gemm<<<g, 256, 0, stream>>>(acat, KCAT, dwbw, DDIM, 128, DDIM, 1,
                                  preG, nullptr, 128, nullptr, nullptr, nullptr);
  }

  // 5. elementwise delta / A_bar_log / B_bar
  k_delta<<<(MROWS * HDIM) / 256, 256, 0, stream>>>(preG, dbv, Bb, Aarr, Alog, Bbar);

  // 6. selective scan -> h (bf16) into acat cols [1024,1088)
  k_scan<<<BDIM * HDIM, 256, 0, stream>>>(Alog, Bbar, acat);

  // 7. u = (h@Cw.T + xc@Dw.T + Cb + Db) * silu(z)   (K=1088 concat GEMM)
  {
    dim3 g(DDIM / 128, MROWS / 128);
    k_gemm<<<g, 256, 0, stream>>>(acat, KCAT, bcat, KCAT, DDIM, KCAT, 2,
                                  nullptr, xn, DDIM, biasCD, z, nullptr);
  }

  // 8. out = u @ Wlast.T + x
  {
    dim3 g(DDIM / 128, MROWS / 128);
    k_gemm<<<g, 256, 0, stream>>>(xn, DDIM, wlb, DDIM, DDIM, DDIM, 3,
                                  outF, nullptr, DDIM, nullptr, nullptr, x);
  }

  (void)in_sizes; (void)n_in; (void)out_size; (void)ws_size;
}

// Round 2
// 761.791 us; speedup vs baseline: 1.2448x; 1.2448x over previous
//
#include <hip/hip_runtime.h>
#include <stdint.h>
#include <stddef.h>

#define TDIM 4096
#define DDIM 1024
#define HDIM 64
#define BDIM 8
#define MROWS (BDIM * TDIM)   // 32768
#define KCAT (DDIM + HDIM)    // 1088

typedef unsigned short ushort_t;
typedef __attribute__((ext_vector_type(8))) short short8;
typedef __attribute__((ext_vector_type(4))) float floatx4;

__device__ __forceinline__ unsigned short f2bf(float f) {
  unsigned u = __float_as_uint(f);
  u += 0x7fffu + ((u >> 16) & 1u);          // round-to-nearest-even
  return (unsigned short)(u >> 16);
}
__device__ __forceinline__ float bf2f(unsigned short s) {
  return __uint_as_float(((unsigned)s) << 16);
}
__device__ __forceinline__ float softplusf(float x) {
  return x > 20.f ? x : log1pf(expf(x));
}

// ---------------- weight conversion helpers ----------------
__global__ void k_cvt(const float* __restrict__ src, ushort_t* __restrict__ dst, int n) {
  int i = blockIdx.x * blockDim.x + threadIdx.x;
  if (i < n) dst[i] = f2bf(src[i]);
}

// Bcat[n][k] : k<1024 -> Dw[n][k], else Cw[n][k-1024]
__global__ void k_bcat(const float* __restrict__ Dw, const float* __restrict__ Cw,
                       ushort_t* __restrict__ bcat) {
  int i = blockIdx.x * blockDim.x + threadIdx.x;
  if (i >= DDIM * KCAT) return;
  int row = i / KCAT, k = i - row * KCAT;
  float v = (k < DDIM) ? Dw[row * DDIM + k] : Cw[row * HDIM + (k - DDIM)];
  bcat[i] = f2bf(v);
}

__global__ void k_bias(const float* __restrict__ Cb, const float* __restrict__ Db,
                       float* __restrict__ biasCD) {
  int i = blockIdx.x * blockDim.x + threadIdx.x;
  if (i < DDIM) biasCD[i] = Cb[i] + Db[i];
}

// ---------------- RMSNorm: x (f32) -> xn (bf16) ----------------
__global__ __launch_bounds__(256) void k_rms(const float* __restrict__ x,
                                             const float* __restrict__ nw,
                                             ushort_t* __restrict__ xn) {
  const int row = blockIdx.x;
  const int tid = threadIdx.x;
  const size_t base = (size_t)row * DDIM + tid * 4;
  const float4 xv = *(const float4*)(x + base);
  float ss = xv.x * xv.x + xv.y * xv.y + xv.z * xv.z + xv.w * xv.w;
  for (int off = 32; off > 0; off >>= 1) ss += __shfl_down(ss, off, 64);
  __shared__ float sws[4];
  const int lane = tid & 63, w = tid >> 6;
  if (lane == 0) sws[w] = ss;
  __syncthreads();
  const float tot = sws[0] + sws[1] + sws[2] + sws[3];
  const float scale = rsqrtf(tot * (1.0f / DDIM) + 1.1920929e-7f);
  const float4 nwv = *(const float4*)(nw + tid * 4);
  ushort4 o;
  o.x = f2bf(xv.x * scale * nwv.x);
  o.y = f2bf(xv.y * scale * nwv.y);
  o.z = f2bf(xv.z * scale * nwv.z);
  o.w = f2bf(xv.w * scale * nwv.w);
  *(ushort4*)(xn + base) = o;
}

// ---------------- causal depthwise conv k=3 + silu: xz[:,0:1024] -> acat[:,0:1024] ----------------
__global__ __launch_bounds__(256) void k_conv(const ushort_t* __restrict__ xz,
                                              const float* __restrict__ cw,
                                              const float* __restrict__ cb,
                                              ushort_t* __restrict__ acat) {
  const size_t idx = (size_t)blockIdx.x * 256 + threadIdx.x;  // over MROWS*DDIM
  const int d = (int)(idx & (DDIM - 1));
  const size_t m = idx >> 10;
  const int t = (int)(m & (TDIM - 1));
  const size_t s = m * 2048 + d;
  const float w0 = cw[d * 3 + 0], w1 = cw[d * 3 + 1], w2 = cw[d * 3 + 2];
  float v = bf2f(xz[s]) * w2;
  if (t >= 1) v += bf2f(xz[s - 2048]) * w1;
  if (t >= 2) v += bf2f(xz[s - 4096]) * w0;
  v += cb[d];
  const float sv = v / (1.f + __expf(-v));
  acat[m * KCAT + d] = f2bf(sv);
}

// ---------------- fused delta + selective scan: one block per (b,h) channel ----------------
// reads preG (M x 128 f32: [:,0:64]=xc@dw.T, [:,64:128]=xc@Bw.T), writes hT[h][b*T + t] bf16
__global__ __launch_bounds__(256) void k_scan(const float* __restrict__ preG,
                                              const float* __restrict__ db,
                                              const float* __restrict__ Bb,
                                              const float* __restrict__ A,
                                              ushort_t* __restrict__ hT) {
  const int ch = blockIdx.x;           // 0..511
  const int b = ch >> 6, h = ch & 63;
  const int tid = threadIdx.x;
  const float dbh = db[h], Bbh = Bb[h];
  const float al = -softplusf(A[h]);
  const size_t base = ((size_t)b * TDIM + (size_t)tid * 16) * 128 + h;

  float a[16], bbv[16];
#pragma unroll
  for (int k = 0; k < 16; ++k) {
    const float p1 = preG[base + (size_t)k * 128];
    const float p2 = preG[base + (size_t)k * 128 + 64];
    const float delta = softplusf(p1 + dbh);
    a[k] = delta * al;
    bbv[k] = delta * (p2 + Bbh);
  }
  float run = 0.f;
#pragma unroll
  for (int k = 0; k < 16; ++k) { run += a[k]; a[k] = run; }  // local inclusive

  __shared__ float sh[256];
  sh[tid] = run;
  __syncthreads();
  for (int s = 1; s < 256; s <<= 1) {
    float v = (tid >= s) ? sh[tid - s] : 0.f;
    __syncthreads();
    sh[tid] += v;
    __syncthreads();
  }
  const float off = (tid > 0) ? sh[tid - 1] : 0.f;
  __syncthreads();

  float term[16];
  float prev = off;  // exclusive prefix (unclipped)
#pragma unroll
  for (int k = 0; k < 16; ++k) {
    const float Pk = off + a[k];
    const float Ashift = fminf(fmaxf(prev, -20.f), 20.f);
    term[k] = bbv[k] * expf(-Ashift);
    a[k] = fminf(fmaxf(Pk, -20.f), 20.f);  // clipped A_cum
    prev = Pk;
  }

  float run2 = 0.f;
#pragma unroll
  for (int k = 0; k < 16; ++k) { run2 += term[k]; term[k] = run2; }
  sh[tid] = run2;
  __syncthreads();
  for (int s = 1; s < 256; s <<= 1) {
    float v = (tid >= s) ? sh[tid - s] : 0.f;
    __syncthreads();
    sh[tid] += v;
    __syncthreads();
  }
  const float off2 = (tid > 0) ? sh[tid - 1] : 0.f;

  ushort_t* dst = hT + (size_t)h * MROWS + (size_t)b * TDIM + (size_t)tid * 16;
#pragma unroll
  for (int k = 0; k < 16; ++k) {
    dst[k] = f2bf(expf(a[k]) * (off2 + term[k]));
  }
}

// ---------------- transpose hT[64][M] -> acat[:, 1024:1088] ----------------
__global__ __launch_bounds__(256) void k_htrans(const ushort_t* __restrict__ hT,
                                                ushort_t* __restrict__ acat) {
  __shared__ ushort_t t[64 * 256];
  const int tid = threadIdx.x;
  const int m0 = blockIdx.x * 256;
#pragma unroll
  for (int p = 0; p < 8; ++p) {
    const int e = p * 2048 + tid * 8;
    const int h = e >> 8, mm = e & 255;
    *(short8*)(t + e) = *(const short8*)(hT + (size_t)h * MROWS + m0 + mm);
  }
  __syncthreads();
  ushort_t* dst = acat + (size_t)(m0 + tid) * KCAT + DDIM;
#pragma unroll
  for (int p = 0; p < 8; ++p) {
    short8 v;
#pragma unroll
    for (int e = 0; e < 8; ++e) v[e] = t[(p * 8 + e) * 256 + tid];
    *(short8*)(dst + p * 8) = v;
  }
}

// ---------------- GEMM: C[m,n] = sum_k A[m,k] * Bt[n,k], bf16 MFMA ----------------
// 128x128 tile, BK=64, 256 threads (4 waves, each 64x64 as 4x4 16x16 frags).
// Linear grid with XCD-aware swizzle: bid%8 -> XCD, n-fast within XCD for A-strip L2 reuse.
// Staging via global_load_lds(16B) with XOR-chunk swizzle. LDS-staged coalesced epilogue.
__device__ __forceinline__ void stage128x64(const ushort_t* __restrict__ G, int row0,
                                            int ld, int kc, ushort_t* s, int wave, int lane) {
  const int rsub = lane >> 3;   // row within 8-row group
  const int cpos = lane & 7;    // dest chunk position
  using gp_t = const unsigned int __attribute__((address_space(1)))*;
  using lp_t = unsigned int __attribute__((address_space(3)))*;
#pragma unroll
  for (int g = 0; g < 4; ++g) {
    const int rg = wave * 4 + g;           // 0..15 row-group
    const int r = rg * 8 + rsub;           // tile row
    const int c = cpos ^ rsub;             // source chunk (r&7 == rsub)
    const ushort_t* src = G + (size_t)(row0 + r) * (size_t)ld + (size_t)(kc + c * 8);
    __builtin_amdgcn_global_load_lds((gp_t)(const void*)src, (lp_t)(void*)(s + rg * 512),
                                     16, 0, 0);
  }
}

__global__ __launch_bounds__(256, 3) void k_gemm(
    const ushort_t* __restrict__ A, int lda,
    const ushort_t* __restrict__ Bt, int ldb,
    int nB, int Kdim, int mode,
    float* __restrict__ outF, ushort_t* __restrict__ outB, int ldc,
    const float* __restrict__ bias,
    const ushort_t* __restrict__ zmat, int ldz,
    const float* __restrict__ resid) {
  __shared__ alignas(16) ushort_t smem[128 * 128];  // 32KB: sA | sB, reused as C-tile
  ushort_t* sA = smem;
  ushort_t* sB = smem + 128 * 64;
  const int tid = threadIdx.x;
  const int wave = tid >> 6, lane = tid & 63;

  // XCD swizzle: consecutive slots on one XCD walk n fastest -> A-strip reuse in L2
  const int per = gridDim.x >> 3;
  const int xcd = blockIdx.x & 7, slot = blockIdx.x >> 3;
  const int tile = xcd * per + slot;
  const int m0 = (tile / nB) * 128, n0 = (tile % nB) * 128;

  const int half_m = (wave & 1) * 64, half_n = (wave >> 1) * 64;
  const int quad = lane >> 4, l16 = lane & 15;

  floatx4 acc[4][4];
#pragma unroll
  for (int i = 0; i < 4; ++i)
#pragma unroll
    for (int j = 0; j < 4; ++j) acc[i][j] = floatx4{0.f, 0.f, 0.f, 0.f};

  for (int kc = 0; kc < Kdim; kc += 64) {
    stage128x64(A, m0, lda, kc, sA, wave, lane);
    stage128x64(Bt, n0, ldb, kc, sB, wave, lane);
    __syncthreads();
#pragma unroll
    for (int s = 0; s < 2; ++s) {
      short8 af[4], bfr[4];
#pragma unroll
      for (int i = 0; i < 4; ++i) {
        const int r = half_m + i * 16 + l16;
        const int cp = (s * 4 + quad) ^ (r & 7);
        af[i] = *(const short8*)(sA + r * 64 + cp * 8);
      }
#pragma unroll
      for (int j = 0; j < 4; ++j) {
        const int r = half_n + j * 16 + l16;
        const int cp = (s * 4 + quad) ^ (r & 7);
        bfr[j] = *(const short8*)(sB + r * 64 + cp * 8);
      }
#pragma unroll
      for (int i = 0; i < 4; ++i)
#pragma unroll
        for (int j = 0; j < 4; ++j)
          acc[i][j] = __builtin_amdgcn_mfma_f32_16x16x32_bf16(af[i], bfr[j], acc[i][j], 0, 0, 0);
    }
    __syncthreads();
  }

  // Epilogue through LDS: acc (C/D layout col=lane&15, row=quad*4+reg) -> bf16 tile -> coalesced stores
#pragma unroll
  for (int i = 0; i < 4; ++i)
#pragma unroll
    for (int j = 0; j < 4; ++j)
#pragma unroll
      for (int rg = 0; rg < 4; ++rg) {
        const int r = half_m + i * 16 + quad * 4 + rg;
        const int c = half_n + j * 16 + l16;
        smem[r * 128 + c] = f2bf(acc[i][j][rg]);
      }
  __syncthreads();

#pragma unroll
  for (int p = 0; p < 8; ++p) {
    const int r = p * 16 + (tid >> 4);
    const int c = (tid & 15) * 8;
    short8 v8 = *(const short8*)(smem + r * 128 + c);
    const size_t m = (size_t)(m0 + r);
    const int n = n0 + c;
    if (mode == 0) {
      *(short8*)(outB + m * (size_t)ldc + n) = v8;
    } else if (mode == 1) {
      float* o = outF + m * (size_t)ldc + n;
#pragma unroll
      for (int e = 0; e < 8; ++e) o[e] = bf2f((ushort_t)v8[e]);
    } else if (mode == 2) {
      const short8 z8 = *(const short8*)(zmat + m * (size_t)ldz + n);
      short8 o;
#pragma unroll
      for (int e = 0; e < 8; ++e) {
        const float v = bf2f((ushort_t)v8[e]) + bias[n + e];
        const float zf = bf2f((ushort_t)z8[e]);
        o[e] = (short)f2bf(v * (zf / (1.f + __expf(-zf))));
      }
      *(short8*)(outB + m * (size_t)ldc + n) = o;
    } else {
      const float* rs = resid + m * (size_t)ldc + n;
      float* o = outF + m * (size_t)ldc + n;
#pragma unroll
      for (int e = 0; e < 8; ++e) o[e] = bf2f((ushort_t)v8[e]) + rs[e];
    }
  }
}

// ---------------- host ----------------
extern "C" void kernel_launch(void* const* d_in, const int* in_sizes, int n_in,
                              void* d_out, int out_size, void* d_ws, size_t ws_size,
                              hipStream_t stream) {
  const float* x      = (const float*)d_in[0];
  const float* norm_w = (const float*)d_in[1];
  const float* W1     = (const float*)d_in[2];
  const float* W2     = (const float*)d_in[3];
  const float* Wlast  = (const float*)d_in[4];
  const float* conv_w = (const float*)d_in[5];
  const float* conv_b = (const float*)d_in[6];
  const float* Aarr   = (const float*)d_in[7];
  const float* Bw     = (const float*)d_in[8];
  const float* Bb     = (const float*)d_in[9];
  const float* Cw     = (const float*)d_in[10];
  const float* Cb     = (const float*)d_in[11];
  const float* Dw     = (const float*)d_in[12];
  const float* Db     = (const float*)d_in[13];
  const float* dwm    = (const float*)d_in[14];
  const float* dbv    = (const float*)d_in[15];

  char* ws = (char*)d_ws;
  // workspace plan (bytes):
  ushort_t* xz   = (ushort_t*)(ws + 0);           // M x 2048 bf16 (x_b | z), 128 MB
  ushort_t* acat = (ushort_t*)(ws + 134217728);   // M x 1088 bf16 (xc | h), ~68 MB
  float*   preG  = (float*)(ws + 205520896);      // M x 128 f32, 16 MB
  ushort_t* hT   = (ushort_t*)(ws + 222298112);   // 64 x M bf16, 4 MB
  ushort_t* xnu  = (ushort_t*)(ws + 226492416);   // M x 1024 bf16: xn, later u. 64 MB
  ushort_t* wcat = (ushort_t*)(ws + 293601280);   // 2048 x 1024 bf16 (W1; W2), 4 MB
  ushort_t* wlb  = (ushort_t*)(ws + 297795584);   // 1024 x 1024 bf16, 2 MB
  ushort_t* dwbw = (ushort_t*)(ws + 299892736);   // 128 x 1024 bf16 (dw; Bw), 256 KB
  ushort_t* bcat = (ushort_t*)(ws + 300154880);   // 1024 x 1088 bf16 (Dw | Cw), ~2.2 MB
  float*  biasCD = (float*)(ws + 302383104);      // 1024 f32
  float*   outF  = (float*)d_out;

  // weight conversions
  k_cvt<<<4096, 256, 0, stream>>>(W1, wcat, DDIM * DDIM);
  k_cvt<<<4096, 256, 0, stream>>>(W2, wcat + DDIM * DDIM, DDIM * DDIM);
  k_cvt<<<4096, 256, 0, stream>>>(Wlast, wlb, DDIM * DDIM);
  k_cvt<<<256, 256, 0, stream>>>(dwm, dwbw, HDIM * DDIM);
  k_cvt<<<256, 256, 0, stream>>>(Bw, dwbw + HDIM * DDIM, HDIM * DDIM);
  k_bcat<<<(DDIM * KCAT + 255) / 256, 256, 0, stream>>>(Dw, Cw, bcat);
  k_bias<<<4, 256, 0, stream>>>(Cb, Db, biasCD);

  // 1. RMSNorm -> xn
  k_rms<<<MROWS, 256, 0, stream>>>(x, norm_w, xnu);

  // 2. [x_b | z] = xn @ [W1;W2].T  (fused, N=2048)
  k_gemm<<<256 * 16, 256, 0, stream>>>(xnu, DDIM, wcat, DDIM, 16, DDIM, 0,
                                       nullptr, xz, 2048, nullptr, nullptr, 0, nullptr);

  // 3. conv + silu -> acat cols [0,1024)
  k_conv<<<(MROWS * DDIM) / 256, 256, 0, stream>>>(xz, conv_w, conv_b, acat);

  // 4. preG = xc @ [dw|Bw].T  (N=128, f32 out)
  k_gemm<<<256 * 1, 256, 0, stream>>>(acat, KCAT, dwbw, DDIM, 1, DDIM, 1,
                                      preG, nullptr, 128, nullptr, nullptr, 0, nullptr);

  // 5+6. fused delta + selective scan -> hT (transposed)
  k_scan<<<BDIM * HDIM, 256, 0, stream>>>(preG, dbv, Bb, Aarr, hT);

  // 6b. transpose hT into acat cols [1024,1088)
  k_htrans<<<MROWS / 256, 256, 0, stream>>>(hT, acat);

  // 7. u = (h@Cw.T + xc@Dw.T + Cb + Db) * silu(z)   (K=1088 concat GEMM)
  k_gemm<<<256 * 8, 256, 0, stream>>>(acat, KCAT, bcat, KCAT, 8, KCAT, 2,
                                      nullptr, xnu, DDIM, biasCD, xz + DDIM, 2048, nullptr);

  // 8. out = u @ Wlast.T + x
  k_gemm<<<256 * 8, 256, 0, stream>>>(xnu, DDIM, wlb, DDIM, 8, DDIM, 3,
                                      outF, nullptr, DDIM, nullptr, nullptr, 0, x);

  (void)in_sizes; (void)n_in; (void)out_size; (void)ws_size;
}

// Round 3
// 682.061 us; speedup vs baseline: 1.3904x; 1.1169x over previous
//
#include <hip/hip_runtime.h>
#include <stdint.h>
#include <stddef.h>

#define TDIM 4096
#define DDIM 1024
#define HDIM 64
#define BDIM 8
#define MROWS (BDIM * TDIM)   // 32768
#define KCAT (DDIM + HDIM)    // 1088
#define DD (DDIM * DDIM)
#define HD (HDIM * DDIM)

typedef unsigned short ushort_t;
typedef __attribute__((ext_vector_type(8))) short short8;
typedef __attribute__((ext_vector_type(4))) float floatx4;

__device__ __forceinline__ unsigned short f2bf(float f) {
  unsigned u = __float_as_uint(f);
  u += 0x7fffu + ((u >> 16) & 1u);          // round-to-nearest-even
  return (unsigned short)(u >> 16);
}
__device__ __forceinline__ float bf2f(unsigned short s) {
  return __uint_as_float(((unsigned)s) << 16);
}
__device__ __forceinline__ float softplusf(float x) {
  return x > 20.f ? x : log1pf(expf(x));
}

// ---------------- fused weight prep (one launch) ----------------
__global__ void k_prep(const float* __restrict__ W1, const float* __restrict__ W2,
                       const float* __restrict__ Wlast, const float* __restrict__ dwm,
                       const float* __restrict__ Bw, const float* __restrict__ Dw,
                       const float* __restrict__ Cw, const float* __restrict__ Cb,
                       const float* __restrict__ Db,
                       ushort_t* __restrict__ wcat, ushort_t* __restrict__ wlb,
                       ushort_t* __restrict__ dwbw, ushort_t* __restrict__ bcat,
                       float* __restrict__ biasCD) {
  int i = blockIdx.x * 256 + threadIdx.x;
  if (i < DD) { wcat[i] = f2bf(W1[i]); return; }
  i -= DD;
  if (i < DD) { wcat[DD + i] = f2bf(W2[i]); return; }
  i -= DD;
  if (i < DD) { wlb[i] = f2bf(Wlast[i]); return; }
  i -= DD;
  if (i < HD) { dwbw[i] = f2bf(dwm[i]); return; }
  i -= HD;
  if (i < HD) { dwbw[HD + i] = f2bf(Bw[i]); return; }
  i -= HD;
  if (i < DDIM * KCAT) {
    const int row = i / KCAT, k = i - row * KCAT;
    const float v = (k < DDIM) ? Dw[row * DDIM + k] : Cw[row * HDIM + (k - DDIM)];
    bcat[i] = f2bf(v);
    return;
  }
  i -= DDIM * KCAT;
  if (i < DDIM) biasCD[i] = Cb[i] + Db[i];
}

// ---------------- RMSNorm: x (f32) -> xn (bf16) ----------------
__global__ __launch_bounds__(256) void k_rms(const float* __restrict__ x,
                                             const float* __restrict__ nw,
                                             ushort_t* __restrict__ xn) {
  const int row = blockIdx.x;
  const int tid = threadIdx.x;
  const size_t base = (size_t)row * DDIM + tid * 4;
  const float4 xv = *(const float4*)(x + base);
  float ss = xv.x * xv.x + xv.y * xv.y + xv.z * xv.z + xv.w * xv.w;
  for (int off = 32; off > 0; off >>= 1) ss += __shfl_down(ss, off, 64);
  __shared__ float sws[4];
  const int lane = tid & 63, w = tid >> 6;
  if (lane == 0) sws[w] = ss;
  __syncthreads();
  const float tot = sws[0] + sws[1] + sws[2] + sws[3];
  const float scale = rsqrtf(tot * (1.0f / DDIM) + 1.1920929e-7f);
  const float4 nwv = *(const float4*)(nw + tid * 4);
  ushort4 o;
  o.x = f2bf(xv.x * scale * nwv.x);
  o.y = f2bf(xv.y * scale * nwv.y);
  o.z = f2bf(xv.z * scale * nwv.z);
  o.w = f2bf(xv.w * scale * nwv.w);
  *(ushort4*)(xn + base) = o;
}

// ---------------- causal depthwise conv k=3 + silu (vectorized x8) ----------------
__global__ __launch_bounds__(256) void k_conv(const ushort_t* __restrict__ xz,
                                              const float* __restrict__ cw,
                                              const float* __restrict__ cb,
                                              ushort_t* __restrict__ acat) {
  const size_t eidx = ((size_t)blockIdx.x * 256 + threadIdx.x) * 8;  // over MROWS*DDIM
  const int d = (int)(eidx & (DDIM - 1));
  const size_t m = eidx >> 10;
  const int t = (int)(m & (TDIM - 1));
  const size_t s = m * 2048 + d;
  const short8 r2 = *(const short8*)(xz + s);
  short8 r1 = {0,0,0,0,0,0,0,0}, r0 = {0,0,0,0,0,0,0,0};
  if (t >= 1) r1 = *(const short8*)(xz + s - 2048);
  if (t >= 2) r0 = *(const short8*)(xz + s - 4096);
  short8 o;
#pragma unroll
  for (int e = 0; e < 8; ++e) {
    const int de = d + e;
    float v = bf2f((ushort_t)r2[e]) * cw[de * 3 + 2]
            + bf2f((ushort_t)r1[e]) * cw[de * 3 + 1]
            + bf2f((ushort_t)r0[e]) * cw[de * 3 + 0]
            + cb[de];
    o[e] = (short)f2bf(v / (1.f + __expf(-v)));
  }
  *(short8*)(acat + m * KCAT + d) = o;
}

// ---------------- fused delta + selective scan: one block per (b,h) channel ----------------
// preG_T is (128 x MROWS) f32: rows 0..63 = xc@dw.T (transposed), rows 64..127 = xc@Bw.T
__global__ __launch_bounds__(256) void k_scan(const float* __restrict__ preG,
                                              const float* __restrict__ db,
                                              const float* __restrict__ Bb,
                                              const float* __restrict__ A,
                                              ushort_t* __restrict__ hT) {
  const int ch = blockIdx.x;           // 0..511
  const int b = ch >> 6, h = ch & 63;
  const int tid = threadIdx.x;
  const float dbh = db[h], Bbh = Bb[h];
  const float al = -softplusf(A[h]);
  const size_t base1 = (size_t)h * MROWS + (size_t)b * TDIM + (size_t)tid * 16;
  const size_t base2 = base1 + (size_t)64 * MROWS;

  float a[16], bbv[16];
#pragma unroll
  for (int k4 = 0; k4 < 4; ++k4) {
    const float4 p1 = *(const float4*)(preG + base1 + k4 * 4);
    const float4 p2 = *(const float4*)(preG + base2 + k4 * 4);
    const float pp1[4] = {p1.x, p1.y, p1.z, p1.w};
    const float pp2[4] = {p2.x, p2.y, p2.z, p2.w};
#pragma unroll
    for (int e = 0; e < 4; ++e) {
      const float delta = softplusf(pp1[e] + dbh);
      a[k4 * 4 + e] = delta * al;
      bbv[k4 * 4 + e] = delta * (pp2[e] + Bbh);
    }
  }
  float run = 0.f;
#pragma unroll
  for (int k = 0; k < 16; ++k) { run += a[k]; a[k] = run; }  // local inclusive

  __shared__ float sh[256];
  sh[tid] = run;
  __syncthreads();
  for (int s = 1; s < 256; s <<= 1) {
    float v = (tid >= s) ? sh[tid - s] : 0.f;
    __syncthreads();
    sh[tid] += v;
    __syncthreads();
  }
  const float off = (tid > 0) ? sh[tid - 1] : 0.f;
  __syncthreads();

  float term[16];
  float prev = off;  // exclusive prefix (unclipped)
#pragma unroll
  for (int k = 0; k < 16; ++k) {
    const float Pk = off + a[k];
    const float Ashift = fminf(fmaxf(prev, -20.f), 20.f);
    term[k] = bbv[k] * expf(-Ashift);
    a[k] = fminf(fmaxf(Pk, -20.f), 20.f);  // clipped A_cum
    prev = Pk;
  }

  float run2 = 0.f;
#pragma unroll
  for (int k = 0; k < 16; ++k) { run2 += term[k]; term[k] = run2; }
  sh[tid] = run2;
  __syncthreads();
  for (int s = 1; s < 256; s <<= 1) {
    float v = (tid >= s) ? sh[tid - s] : 0.f;
    __syncthreads();
    sh[tid] += v;
    __syncthreads();
  }
  const float off2 = (tid > 0) ? sh[tid - 1] : 0.f;

  ushort_t* dst = hT + (size_t)h * MROWS + (size_t)b * TDIM + (size_t)tid * 16;
#pragma unroll
  for (int k = 0; k < 16; ++k) {
    dst[k] = f2bf(expf(a[k]) * (off2 + term[k]));
  }
}

// ---------------- transpose hT[64][M] -> acat[:, 1024:1088] ----------------
__global__ __launch_bounds__(256) void k_htrans(const ushort_t* __restrict__ hT,
                                                ushort_t* __restrict__ acat) {
  __shared__ ushort_t t[64 * 256];
  const int tid = threadIdx.x;
  const int m0 = blockIdx.x * 256;
#pragma unroll
  for (int p = 0; p < 8; ++p) {
    const int e = p * 2048 + tid * 8;
    const int h = e >> 8, mm = e & 255;
    *(short8*)(t + e) = *(const short8*)(hT + (size_t)h * MROWS + m0 + mm);
  }
  __syncthreads();
  ushort_t* dst = acat + (size_t)(m0 + tid) * KCAT + DDIM;
#pragma unroll
  for (int p = 0; p < 8; ++p) {
    short8 v;
#pragma unroll
    for (int e = 0; e < 8; ++e) v[e] = t[(p * 8 + e) * 256 + tid];
    *(short8*)(dst + p * 8) = v;
  }
}

// ---------------- GEMM: C[m,n] = sum_k A[m,k] * Bt[n,k], bf16 MFMA ----------------
// 128x128 tile, BK=64, 256 threads (4 waves, each 64x64 as 4x4 16x16 frags).
// Linear grid with XCD-aware swizzle. global_load_lds(16B) staging with XOR-chunk
// swizzle. LDS-staged coalesced epilogue.
__device__ __forceinline__ void stage128x64(const ushort_t* __restrict__ G, int row0,
                                            int ld, int kc, ushort_t* s, int wave, int lane) {
  const int rsub = lane >> 3;   // row within 8-row group
  const int cpos = lane & 7;    // dest chunk position
  using gp_t = const unsigned int __attribute__((address_space(1)))*;
  using lp_t = unsigned int __attribute__((address_space(3)))*;
#pragma unroll
  for (int g = 0; g < 4; ++g) {
    const int rg = wave * 4 + g;           // 0..15 row-group
    const int r = rg * 8 + rsub;           // tile row
    const int c = cpos ^ rsub;             // source chunk (r&7 == rsub)
    const ushort_t* src = G + (size_t)(row0 + r) * (size_t)ld + (size_t)(kc + c * 8);
    __builtin_amdgcn_global_load_lds((gp_t)(const void*)src, (lp_t)(void*)(s + rg * 512),
                                     16, 0, 0);
  }
}

__global__ __launch_bounds__(256, 4) void k_gemm(
    const ushort_t* __restrict__ A, int lda,
    const ushort_t* __restrict__ Bt, int ldb,
    int nB, int Kdim, int mode,
    float* __restrict__ outF, ushort_t* __restrict__ outB, int ldc,
    const float* __restrict__ bias,
    const ushort_t* __restrict__ zmat, int ldz,
    const float* __restrict__ resid) {
  __shared__ alignas(16) ushort_t smem[128 * 128];  // 32KB: sA | sB, reused as C-tile
  ushort_t* sA = smem;
  ushort_t* sB = smem + 128 * 64;
  const int tid = threadIdx.x;
  const int wave = tid >> 6, lane = tid & 63;

  // XCD swizzle: consecutive slots on one XCD walk n fastest -> A-strip reuse in L2
  const int per = gridDim.x >> 3;
  const int xcd = blockIdx.x & 7, slot = blockIdx.x >> 3;
  const int tile = xcd * per + slot;
  const int m0 = (tile / nB) * 128, n0 = (tile % nB) * 128;

  const int half_m = (wave & 1) * 64, half_n = (wave >> 1) * 64;
  const int quad = lane >> 4, l16 = lane & 15;

  floatx4 acc[4][4];
#pragma unroll
  for (int i = 0; i < 4; ++i)
#pragma unroll
    for (int j = 0; j < 4; ++j) acc[i][j] = floatx4{0.f, 0.f, 0.f, 0.f};

  for (int kc = 0; kc < Kdim; kc += 64) {
    stage128x64(A, m0, lda, kc, sA, wave, lane);
    stage128x64(Bt, n0, ldb, kc, sB, wave, lane);
    __syncthreads();
#pragma unroll
    for (int s = 0; s < 2; ++s) {
      short8 af[4], bfr[4];
#pragma unroll
      for (int i = 0; i < 4; ++i) {
        const int r = half_m + i * 16 + l16;
        const int cp = (s * 4 + quad) ^ (r & 7);
        af[i] = *(const short8*)(sA + r * 64 + cp * 8);
      }
#pragma unroll
      for (int j = 0; j < 4; ++j) {
        const int r = half_n + j * 16 + l16;
        const int cp = (s * 4 + quad) ^ (r & 7);
        bfr[j] = *(const short8*)(sB + r * 64 + cp * 8);
      }
#pragma unroll
      for (int i = 0; i < 4; ++i)
#pragma unroll
        for (int j = 0; j < 4; ++j)
          acc[i][j] = __builtin_amdgcn_mfma_f32_16x16x32_bf16(af[i], bfr[j], acc[i][j], 0, 0, 0);
    }
    __syncthreads();
  }

  // Epilogue through LDS: acc (C/D layout col=lane&15, row=quad*4+reg) -> bf16 tile
#pragma unroll
  for (int i = 0; i < 4; ++i)
#pragma unroll
    for (int j = 0; j < 4; ++j)
#pragma unroll
      for (int rg = 0; rg < 4; ++rg) {
        const int r = half_m + i * 16 + quad * 4 + rg;
        const int c = half_n + j * 16 + l16;
        smem[r * 128 + c] = f2bf(acc[i][j][rg]);
      }
  __syncthreads();

#pragma unroll
  for (int p = 0; p < 8; ++p) {
    const int r = p * 16 + (tid >> 4);
    const int c = (tid & 15) * 8;
    short8 v8 = *(const short8*)(smem + r * 128 + c);
    const size_t m = (size_t)(m0 + r);
    const int n = n0 + c;
    if (mode == 0) {
      *(short8*)(outB + m * (size_t)ldc + n) = v8;
    } else if (mode == 1) {
      float* o = outF + m * (size_t)ldc + n;
#pragma unroll
      for (int e = 0; e < 8; ++e) o[e] = bf2f((ushort_t)v8[e]);
    } else if (mode == 2) {
      const short8 z8 = *(const short8*)(zmat + m * (size_t)ldz + n);
      short8 o;
#pragma unroll
      for (int e = 0; e < 8; ++e) {
        const float v = bf2f((ushort_t)v8[e]) + bias[n + e];
        const float zf = bf2f((ushort_t)z8[e]);
        o[e] = (short)f2bf(v * (zf / (1.f + __expf(-zf))));
      }
      *(short8*)(outB + m * (size_t)ldc + n) = o;
    } else {
      const float* rs = resid + m * (size_t)ldc + n;
      float* o = outF + m * (size_t)ldc + n;
#pragma unroll
      for (int e = 0; e < 8; ++e) o[e] = bf2f((ushort_t)v8[e]) + rs[e];
    }
  }
}

// ---------------- host ----------------
extern "C" void kernel_launch(void* const* d_in, const int* in_sizes, int n_in,
                              void* d_out, int out_size, void* d_ws, size_t ws_size,
                              hipStream_t stream) {
  const float* x      = (const float*)d_in[0];
  const float* norm_w = (const float*)d_in[1];
  const float* W1     = (const float*)d_in[2];
  const float* W2     = (const float*)d_in[3];
  const float* Wlast  = (const float*)d_in[4];
  const float* conv_w = (const float*)d_in[5];
  const float* conv_b = (const float*)d_in[6];
  const float* Aarr   = (const float*)d_in[7];
  const float* Bw     = (const float*)d_in[8];
  const float* Bb     = (const float*)d_in[9];
  const float* Cw     = (const float*)d_in[10];
  const float* Cb     = (const float*)d_in[11];
  const float* Dw     = (const float*)d_in[12];
  const float* Db     = (const float*)d_in[13];
  const float* dwm    = (const float*)d_in[14];
  const float* dbv    = (const float*)d_in[15];

  char* ws = (char*)d_ws;
  // workspace plan (bytes):
  ushort_t* xz   = (ushort_t*)(ws + 0);           // M x 2048 bf16 (x_b | z), 128 MB
  ushort_t* acat = (ushort_t*)(ws + 134217728);   // M x 1088 bf16 (xc | h), ~68 MB
  float*   preG  = (float*)(ws + 205520896);      // 128 x M f32 (transposed), 16 MB
  ushort_t* hT   = (ushort_t*)(ws + 222298112);   // 64 x M bf16, 4 MB
  ushort_t* xnu  = (ushort_t*)(ws + 226492416);   // M x 1024 bf16: xn, later u. 64 MB
  ushort_t* wcat = (ushort_t*)(ws + 293601280);   // 2048 x 1024 bf16 (W1; W2), 4 MB
  ushort_t* wlb  = (ushort_t*)(ws + 297795584);   // 1024 x 1024 bf16, 2 MB
  ushort_t* dwbw = (ushort_t*)(ws + 299892736);   // 128 x 1024 bf16 (dw; Bw), 256 KB
  ushort_t* bcat = (ushort_t*)(ws + 300154880);   // 1024 x 1088 bf16 (Dw | Cw), ~2.2 MB
  float*  biasCD = (float*)(ws + 302383104);      // 1024 f32
  float*   outF  = (float*)d_out;

  // 0. fused weight prep (one launch)
  {
    const int total = 3 * DD + 2 * HD + DDIM * KCAT + DDIM;
    k_prep<<<(total + 255) / 256, 256, 0, stream>>>(W1, W2, Wlast, dwm, Bw, Dw, Cw, Cb, Db,
                                                    wcat, wlb, dwbw, bcat, biasCD);
  }

  // 1. RMSNorm -> xn
  k_rms<<<MROWS, 256, 0, stream>>>(x, norm_w, xnu);

  // 2. [x_b | z] = xn @ [W1;W2].T  (fused, N=2048)
  k_gemm<<<256 * 16, 256, 0, stream>>>(xnu, DDIM, wcat, DDIM, 16, DDIM, 0,
                                       nullptr, xz, 2048, nullptr, nullptr, 0, nullptr);

  // 3. conv + silu -> acat cols [0,1024)
  k_conv<<<(MROWS * DDIM) / (256 * 8), 256, 0, stream>>>(xz, conv_w, conv_b, acat);

  // 4. preG_T = [dw;Bw] @ xc.T  (operand-swapped: output 128 x M row-major, coalesced)
  k_gemm<<<256, 256, 0, stream>>>(dwbw, DDIM, acat, KCAT, 256, DDIM, 1,
                                  preG, nullptr, MROWS, nullptr, nullptr, 0, nullptr);

  // 5+6. fused delta + selective scan -> hT (transposed)
  k_scan<<<BDIM * HDIM, 256, 0, stream>>>(preG, dbv, Bb, Aarr, hT);

  // 6b. transpose hT into acat cols [1024,1088)
  k_htrans<<<MROWS / 256, 256, 0, stream>>>(hT, acat);

  // 7. u = (h@Cw.T + xc@Dw.T + Cb + Db) * silu(z)   (K=1088 concat GEMM)
  k_gemm<<<256 * 8, 256, 0, stream>>>(acat, KCAT, bcat, KCAT, 8, KCAT, 2,
                                      nullptr, xnu, DDIM, biasCD, xz + DDIM, 2048, nullptr);

  // 8. out = u @ Wlast.T + x
  k_gemm<<<256 * 8, 256, 0, stream>>>(xnu, DDIM, wlb, DDIM, 8, DDIM, 3,
                                      outF, nullptr, DDIM, nullptr, nullptr, 0, x);

  (void)in_sizes; (void)n_in; (void)out_size; (void)ws_size;
}